// Round 10
// baseline (2967.737 us; speedup 1.0000x reference)
//
#include <hip/hip_runtime.h>

#define BB 32
#define TT 1000
#define HH 512
#define G4 2048
#define BTH ((size_t)BB * TT * HH)  // elements per output tensor

typedef short short8 __attribute__((ext_vector_type(8)));
typedef float f32x4 __attribute__((ext_vector_type(4)));

__device__ __forceinline__ unsigned short f2bf(float f) {
    union { float f; unsigned u; } v; v.f = f;
    unsigned r = v.u + 0x7FFF + ((v.u >> 16) & 1);  // RNE; inputs finite
    return (unsigned short)(r >> 16);
}

// ring: u32 words [2 slots][8 groups][32 producers x 64 words]
// word = (bf16(h) << 16) | t  -- self-tagged, fence-free (R2-proven protocol)
#define RING_WORDS (2 * 8 * 32 * 64)   // 32768 u32 = 128KB (proven within ws_size)

__global__ void lstm_init_ring(unsigned* ring) {
    int i = blockIdx.x * 256 + threadIdx.x;
    __hip_atomic_store(ring + i, 0xFFFFFFFFu, __ATOMIC_RELAXED,
                       __HIP_MEMORY_SCOPE_AGENT);
}

// LDS-ordering-only barrier (R9-validated neutral-safe): VMEM stays in flight.
#define LDS_BAR() do {                                      \
    asm volatile("s_waitcnt lgkmcnt(0)" ::: "memory");      \
    __builtin_amdgcn_s_barrier();                           \
    asm volatile("" ::: "memory");                          \
    __builtin_amdgcn_sched_barrier(0);                      \
} while (0)

__global__ void __launch_bounds__(256, 1)
lstm_main(const float* __restrict__ wx, const float* __restrict__ u,
          const float* __restrict__ ub, const float* __restrict__ ht0,
          const float* __restrict__ ct0, float* __restrict__ out,
          unsigned* __restrict__ ring)
{
    // Double-buffered h (32KB) + double-buffered gates (2KB) + flags (128B).
    __shared__ __align__(16) unsigned short lds_h[2][16 * 512];
    __shared__ float lds_gates[2][4 * 64];
    __shared__ int flagsum[32];   // monotonic: 8 chunk-pollers x +1 per step

    const int tid  = threadIdx.x;
    const int bid  = blockIdx.x;
    const int cg   = bid & 31;   // owns h/gate cols [cg*16, cg*16+16)
    const int qb   = bid >> 5;   // owns batches [qb*4, qb*4+4)
    const int lane = tid & 63;
    const int wv   = tid >> 6;

    // ---- zero pad rows 4..15 of BOTH h buffers ----
    for (int j = 0; j < 6; ++j) {
        int idx8 = tid + j * 256;             // 1536 x short8
        int buf  = idx8 >= 768;
        int r8   = idx8 - buf * 768;
        int r    = 4 + (r8 >> 6);
        int k    = (r8 & 63) * 8;
        short8 z = {0, 0, 0, 0, 0, 0, 0, 0};
        *(short8*)&lds_h[buf][(r * 512 + k) ^ ((r & 7) << 3)] = z;
    }
    // ---- stage initial h (f32 -> bf16) into buf0 ----
    {
        int r = wv, k = lane * 8;
        const float* src = ht0 + (size_t)(qb * 4 + r) * HH + k;
        float4 v0 = *(const float4*)src;
        float4 v1 = *(const float4*)(src + 4);
        union { short8 v8; unsigned short s[8]; } p;
        p.s[0] = f2bf(v0.x); p.s[1] = f2bf(v0.y); p.s[2] = f2bf(v0.z); p.s[3] = f2bf(v0.w);
        p.s[4] = f2bf(v1.x); p.s[5] = f2bf(v1.y); p.s[6] = f2bf(v1.z); p.s[7] = f2bf(v1.w);
        *(short8*)&lds_h[0][(r * 512 + k) ^ ((r & 7) << 3)] = p.v8;
    }

    // ---- preload u fragments, ROTATED: breg[i] is for kk=(4*wv+i)&15 so all
    //      register indexing stays compile-time (runtime-idx arrays -> scratch) ----
    const int arow = lane & 15, ahi = lane >> 4;
    short8 breg[16];
    {
        const float* bp = u + (size_t)(wv * HH + cg * 16 + arow) * HH + ahi * 8;
#pragma unroll
        for (int i = 0; i < 16; ++i) {
            int kkv = (4 * wv + i) & 15;
            float4 v0 = *(const float4*)(bp + kkv * 32);
            float4 v1 = *(const float4*)(bp + kkv * 32 + 4);
            union { short8 v8; unsigned short s[8]; } p;
            p.s[0] = f2bf(v0.x); p.s[1] = f2bf(v0.y); p.s[2] = f2bf(v0.z); p.s[3] = f2bf(v0.w);
            p.s[4] = f2bf(v1.x); p.s[5] = f2bf(v1.y); p.s[6] = f2bf(v1.z); p.s[7] = f2bf(v1.w);
            breg[i] = p.v8;
        }
    }

    const int gate = lane >> 4;
    const int jc   = lane & 15;
    const float bias_r = ub[gate * HH + cg * 16 + jc];

    float c_reg = 0.f;
    if (lane < 16)
        c_reg = ct0[(size_t)(qb * 4 + wv) * HH + cg * 16 + lane];

    const size_t wx0 = (size_t)(qb * 4 + wv) * TT * G4 + gate * HH + cg * 16 + jc;
    float wx_cur = wx[wx0];
    float wx_nxt = wx[wx0 + G4];

    const size_t ob_gate = (size_t)(2 + gate) * BTH +
                           (size_t)(qb * 4 + wv) * TT * HH + cg * 16 + jc;
    const size_t ob_h = (size_t)(qb * 4 + wv) * TT * HH + cg * 16 + lane;

    const int a_off = arow * 512 + ahi * 8;
    const int a_msk = (arow & 7) << 3;

    const int myp = tid >> 3;            // producer 0..31 (uniform: own too)
    const int mw  = (tid & 7) * 8;       // word offset 0..56
    const int mb  = mw >> 4;
    const int mj  = mw & 15;

    if (tid < 32) flagsum[tid] = 0;
    volatile int* vf = flagsum;

    __syncthreads();   // setup complete

    for (int t = 0; t < TT; ++t) {
        const int cur = t & 1;

        // ---- (A) poll ring(t-1) -> stage lds_h[cur] -> bump flag ----
        // Wave w's lanes poll producers 8w..8w+7 (exactly its first 4 MFMA slots).
        if (t > 0) {
            const unsigned long long* src = (const unsigned long long*)
                (ring + ((size_t)((t - 1) & 1) * 8 + qb) * 2048 + myp * 64 + mw);
            const unsigned tg = (unsigned)(t - 1);
            const unsigned long long want =
                (unsigned long long)tg | ((unsigned long long)tg << 32);
            const unsigned long long msk = 0x0000FFFF0000FFFFull;
            unsigned long long q0, q1, q2, q3;
            for (;;) {
                q0 = __hip_atomic_load(src + 0, __ATOMIC_RELAXED, __HIP_MEMORY_SCOPE_AGENT);
                q1 = __hip_atomic_load(src + 1, __ATOMIC_RELAXED, __HIP_MEMORY_SCOPE_AGENT);
                q2 = __hip_atomic_load(src + 2, __ATOMIC_RELAXED, __HIP_MEMORY_SCOPE_AGENT);
                q3 = __hip_atomic_load(src + 3, __ATOMIC_RELAXED, __HIP_MEMORY_SCOPE_AGENT);
                if (((q0 & msk) == want) & ((q1 & msk) == want) &
                    ((q2 & msk) == want) & ((q3 & msk) == want)) break;
            }
            union { short8 v8; unsigned u[4]; } pv;
            pv.u[0] = ((unsigned)(q0 >> 16) & 0xFFFFu) | ((unsigned)(q0 >> 48) << 16);
            pv.u[1] = ((unsigned)(q1 >> 16) & 0xFFFFu) | ((unsigned)(q1 >> 48) << 16);
            pv.u[2] = ((unsigned)(q2 >> 16) & 0xFFFFu) | ((unsigned)(q2 >> 48) << 16);
            pv.u[3] = ((unsigned)(q3 >> 16) & 0xFFFFu) | ((unsigned)(q3 >> 48) << 16);
            *(short8*)&lds_h[cur][(mb * 512 + myp * 16 + mj) ^ ((mb & 7) << 3)] = pv.v8;
            // data visible before flag: drain LDS write, then monotonic add
            asm volatile("s_waitcnt lgkmcnt(0)" ::: "memory");
            __hip_atomic_fetch_add(&flagsum[myp], 1, __ATOMIC_RELAXED,
                                   __HIP_MEMORY_SCOPE_WORKGROUP);
        }

        const float wx_use = wx_cur;
        wx_cur = wx_nxt;
        if (t + 2 < TT) wx_nxt = wx[wx0 + (size_t)(t + 2) * G4];   // R2 position

        // ---- (B) MFMA, rotated start kk0=4*wv; flag checkpoints at i=4,8,12 ----
        // flagsum[p] >= 8*t <=> producer p's 8 chunks staged for step t (monotonic,
        // no equality race; drift bounded by the LDS_BAR below).
        f32x4 acc0 = {0.f, 0.f, 0.f, 0.f}, acc1 = {0.f, 0.f, 0.f, 0.f};
        const int tgt = 8 * t;
#pragma unroll
        for (int i = 0; i < 16; ++i) {
            if (i == 4 || i == 8 || i == 12) {
                const int pbase = (8 * wv + 2 * i) & 31;   // 8 producers, 8-aligned
                for (;;) {
                    int m0 = vf[pbase + 0], m1 = vf[pbase + 1];
                    int m2 = vf[pbase + 2], m3 = vf[pbase + 3];
                    int m4 = vf[pbase + 4], m5 = vf[pbase + 5];
                    int m6 = vf[pbase + 6], m7 = vf[pbase + 7];
                    int mn = min(min(min(m0, m1), min(m2, m3)),
                                 min(min(m4, m5), min(m6, m7)));
                    if (mn >= tgt) break;
                }
            }
            const int kk = (4 * wv + i) & 15;
            short8 a = *(const short8*)&lds_h[cur][(a_off + kk * 32) ^ a_msk];
            if (i & 1)
                acc1 = __builtin_amdgcn_mfma_f32_16x16x32_bf16(a, breg[i], acc1, 0, 0, 0);
            else
                acc0 = __builtin_amdgcn_mfma_f32_16x16x32_bf16(a, breg[i], acc0, 0, 0, 0);
        }
        f32x4 g = acc0 + acc1;
        if (lane < 16) {
#pragma unroll
            for (int rr = 0; rr < 4; ++rr)
                lds_gates[cur][rr * 64 + wv * 16 + lane] = g[rr];
        }
        LDS_BAR();   // gates handoff; also bounds wave drift to <=1 step

        // ---- (D) epilogue: activations, c/h update, publish (R2-exact) ----
        float gv = lds_gates[cur][wv * 64 + lane] + wx_use + bias_r;
        float xs = (gate == 2) ? 2.f * gv : gv;
        float s  = 1.f / (1.f + __expf(-xs));
        float act = (gate == 2) ? 2.f * s - 1.f : s;  // tanh = 2*sigmoid(2x)-1

        float af = __shfl(act, (lane & 15) + 16, 64);
        float ag = __shfl(act, (lane & 15) + 32, 64);
        float ao = __shfl(act, (lane & 15) + 48, 64);
        if (lane < 16) {
            c_reg = af * c_reg + act * ag;
            float e2 = __expf(-2.f * c_reg);
            float th = 2.f / (1.f + e2) - 1.f;
            float hn = ao * th;
            unsigned short hb = f2bf(hn);
            // publish FIRST (critical inter-block path); own cols come back via ring
            unsigned pk = ((unsigned)hb << 16) | (unsigned)t;
            __hip_atomic_store(ring + ((size_t)(t & 1) * 8 + qb) * 2048 +
                                   cg * 64 + wv * 16 + lane,
                               pk, __ATOMIC_RELAXED, __HIP_MEMORY_SCOPE_AGENT);
            out[ob_h + (size_t)t * HH] = hn;
            out[BTH + ob_h + (size_t)t * HH] = c_reg;
        }
        out[ob_gate + (size_t)t * HH] = act;
    }
}

extern "C" void kernel_launch(void* const* d_in, const int* in_sizes, int n_in,
                              void* d_out, int out_size, void* d_ws, size_t ws_size,
                              hipStream_t stream) {
    const float* wx = (const float*)d_in[0];
    const float* u  = (const float*)d_in[1];
    const float* ub = (const float*)d_in[2];
    const float* ht = (const float*)d_in[3];
    const float* ct = (const float*)d_in[4];
    float* out = (float*)d_out;
    unsigned* ring = (unsigned*)d_ws;   // 128KB, proven within ws_size

    lstm_init_ring<<<RING_WORDS / 256, 256, 0, stream>>>(ring);

    void* args[] = {(void*)&wx, (void*)&u, (void*)&ub, (void*)&ht,
                    (void*)&ct, (void*)&out, (void*)&ring};
    hipLaunchCooperativeKernel((void*)lstm_main, dim3(256), dim3(256), args, 0, stream);
}